// Round 7
// baseline (526.296 us; speedup 1.0000x reference)
//
#include <hip/hip_runtime.h>

#define BB 128
#define NN 512
#define DD 128
#define SLOT_STRIDE 544  // 512 data floats + tag int at [512] + pad (2176 B)

// ---------------- kernel 1: h -> normalized hn ----------------
__global__ __launch_bounds__(256) void hn_kernel(const float* __restrict__ h,
                                                 const float* __restrict__ W0,
                                                 const float* __restrict__ W1,
                                                 float* __restrict__ hn) {
    int wave = (int)((blockIdx.x * blockDim.x + threadIdx.x) >> 6);  // 0..B*N-1
    int lane = threadIdx.x & 63;
    const float2* h2 = (const float2*)(h + (size_t)wave * DD);
    float2 w0 = ((const float2*)W0)[lane];
    float2 w1 = ((const float2*)W1)[lane];
    float2 x = h2[lane];
    float p0 = fmaxf(x.x * w0.x, 0.0f) * w1.x;
    float p1 = fmaxf(x.y * w0.y, 0.0f) * w1.y;
    float ss = p0 * p0 + p1 * p1;
#pragma unroll
    for (int m = 32; m; m >>= 1) ss += __shfl_xor(ss, m);
    float inv = 1.0f / (sqrtf(ss) + 1e-12f);
    float2 o;
    o.x = p0 * inv;
    o.y = p1 * inv;
    ((float2*)(hn + (size_t)wave * DD))[lane] = o;
}

__device__ __forceinline__ float dot8(float4 A, float4 B, float4 x0, float4 x1) {
    float d = fmaf(A.x, x0.x, fmaf(A.y, x0.y, fmaf(A.z, x0.z, A.w * x0.w)));
    return fmaf(B.x, x1.x, fmaf(B.y, x1.y, fmaf(B.z, x1.z, fmaf(B.w, x1.w, d))));
}

// ---------------- persistent Sinkhorn, sim FUSED into the fill ------------
// R22: sim_kernel DELETED. Post-mortem R18-R21: the 20-iter loop is pinned
// at ~7.4us/iter (agent-scope exchange floor) across every phase-A variant,
// so the remaining lever is the OTHER ~230us: sim (fp32 GEMM ~4GFLOP, K
// round-trips 44MB through global) + epi. This round: each block COMPUTES
// its 176 cached K rows from hn via a staged-LDS GEMM using the SAME
// k-sequential fmaf chain as old sim (kc-chunks, kk ascending -> k=0..127
// in order, same expf(2s-2)) => K/u/v/output BITWISE-identical. Rows are
// written to d_out so epi_kernel is untouched. Overflow rows (>176, shrink
// case) are computed in a one-time pass-2 from hn (global reads) and
// streamed from d_out during iterations (d_out doubles as spill -- always
// big enough). Row-skip (omax, wave-uniform) + col-half skip (a1) avoid
// the dead region. LDS: hnT 32K + pv 16K (hnR aliased) + xb 2K + sched 1K
// = 52KB. Exchange protocol byte-identical to R17-R21 (proven).
#define ROWS22(X) X(0) X(1) X(2) X(3) X(4) X(5) X(6) X(7) X(8) X(9) X(10) \
    X(11) X(12) X(13) X(14) X(15) X(16) X(17) X(18) X(19) X(20) X(21)

__global__ __launch_bounds__(512, 2) void coop_sink(const float* __restrict__ hnG,
                                                    float* __restrict__ Kio,
                                                    float* __restrict__ u_buf,
                                                    float* __restrict__ v_buf,
                                                    const int* __restrict__ lengths,
                                                    float* __restrict__ slots) {
    __shared__ float xb[NN];       // current multiplier vector (v)
    __shared__ float pv[8 * NN];   // iter: per-wave partials; fill: hnR alias
    __shared__ float hnT[16][NN];  // fill: transposed hn chunk [k][col], 32 KB
    __shared__ int Sh[BB], Pre[BB];

    int g = blockIdx.x;
    int tid = threadIdx.x;

    // ---- deterministic GLOBAL schedule: S_b = ceil(len/176), sum <= 256 ---
    if (tid == 0) {
        int need[BB]; int ssum = 0;
        for (int m = 0; m < BB; m++) {
            int L = max(lengths[m], 1);
            need[m] = (L + 175) / 176;  // 1..3
            ssum += need[m];
        }
        while (ssum > 256) {  // shrink the largest (first on tie)
            int best = 0, bv = need[0];
            for (int m = 1; m < BB; m++)
                if (need[m] > bv) { bv = need[m]; best = m; }
            need[best]--; ssum--;
        }
        int acc = 0;
        for (int m = 0; m < BB; m++) { Pre[m] = acc; Sh[m] = need[m]; acc += need[m]; }
    }
    __syncthreads();

    int m = -1;
    for (int mm = 0; mm < BB; mm++)
        if (g >= Pre[mm] && g < Pre[mm] + Sh[mm]) { m = mm; break; }
    if (m < 0) return;  // surplus block: idle
    int b = m;                  // batch
    int jbase = Pre[m];
    int q = g - jbase;          // slice within batch
    int S = Sh[m];              // slices for this batch (<=3)

    int len = max(lengths[b], 1);
    int len4 = (len + 3) & ~3;
    int rpq = (len + S - 1) / S;
    int r_lo = q * rpq;
    int nrows = min(len - r_lo, rpq);
    if (nrows < 0) nrows = 0;
    float inv_n = 1.0f / (float)len;

    int w = tid >> 6, l = tid & 63;
    int c0 = 4 * l, c1 = 256 + 4 * l;
    bool a0 = c0 < len4, a1 = c1 < len4;
    const float* hnb = hnG + (size_t)b * NN * DD;
    float* Kb = Kio + (size_t)b * NN * NN;

    xb[tid] = (tid < len) ? 1.0f : 0.0f;

    // rows this wave actually owns: o < omax  (wave-uniform)
    int omax = (nrows > w) ? ((nrows - w + 7) >> 3) : 0;
    if (omax > 22) omax = 22;

    // ---- register-resident K slice: rows w+8o (o<22), named scalars -------
#define DECL(o) float4 kA##o = {0,0,0,0}, kB##o = {0,0,0,0};
    ROWS22(DECL)
#undef DECL

    // ================= fused fill: K rows computed from hn =================
    float (*hnRl)[16] = (float (*)[16])pv;  // fill-time alias: [176][16]
    for (int kc = 0; kc < DD; kc += 16) {
        __syncthreads();  // protect previous chunk's readers
        // stage hnT[k][col] (transposed): 2048 float4, 4 per thread
#pragma unroll
        for (int gg = 0; gg < 4; gg++) {
            int f = tid + (gg << 9);               // 0..2047
            int col = f >> 2, g4 = (f & 3) << 2;   // g4 in {0,4,8,12}
            float4 t4 = *(const float4*)(hnb + (size_t)col * DD + kc + g4);
            hnT[g4 + 0][col] = t4.x; hnT[g4 + 1][col] = t4.y;
            hnT[g4 + 2][col] = t4.z; hnT[g4 + 3][col] = t4.w;
        }
        // stage own rows chunk hnR[row][k]: 176*4 float4
        for (int f = tid; f < 176 * 4; f += 512) {
            int row = f >> 2, g4 = (f & 3) << 2;
            int gr = r_lo + row;
            float4 t4 = {0, 0, 0, 0};
            if (row < nrows && gr < NN)
                t4 = *(const float4*)(hnb + (size_t)gr * DD + kc + g4);
            *(float4*)&hnRl[row][g4] = t4;
        }
        __syncthreads();
        for (int kk = 0; kk < 16; kk++) {
            float4 B0 = *(const float4*)&hnT[kk][c0];
#define GEMM_A(o)                                                            \
            if ((o) < omax) {                                                \
                float a_ = hnRl[w + 8 * (o)][kk];                            \
                kA##o.x = fmaf(a_, B0.x, kA##o.x);                           \
                kA##o.y = fmaf(a_, B0.y, kA##o.y);                           \
                kA##o.z = fmaf(a_, B0.z, kA##o.z);                           \
                kA##o.w = fmaf(a_, B0.w, kA##o.w);                           \
            }
            ROWS22(GEMM_A)
#undef GEMM_A
            if (a1) {
                float4 B1 = *(const float4*)&hnT[kk][c1];
#define GEMM_B(o)                                                            \
                if ((o) < omax) {                                            \
                    float a_ = hnRl[w + 8 * (o)][kk];                        \
                    kB##o.x = fmaf(a_, B1.x, kB##o.x);                       \
                    kB##o.y = fmaf(a_, B1.y, kB##o.y);                       \
                    kB##o.z = fmaf(a_, B1.z, kB##o.z);                       \
                    kB##o.w = fmaf(a_, B1.w, kB##o.w);                       \
                }
                ROWS22(GEMM_B)
#undef GEMM_B
            }
        }
    }
    // diag + exp (identical to old sim's expf(2s-2)), write K rows to d_out
#define FIN_ROW(o)                                                           \
    if ((o) < omax) {                                                        \
        int gi_ = r_lo + w + 8 * (o);                                        \
        kA##o.x = expf(2.0f * (kA##o.x + ((gi_ == c0 + 0) ? 1.0f : 0.0f)) - 2.0f); \
        kA##o.y = expf(2.0f * (kA##o.y + ((gi_ == c0 + 1) ? 1.0f : 0.0f)) - 2.0f); \
        kA##o.z = expf(2.0f * (kA##o.z + ((gi_ == c0 + 2) ? 1.0f : 0.0f)) - 2.0f); \
        kA##o.w = expf(2.0f * (kA##o.w + ((gi_ == c0 + 3) ? 1.0f : 0.0f)) - 2.0f); \
        kB##o.x = expf(2.0f * (kB##o.x + ((gi_ == c1 + 0) ? 1.0f : 0.0f)) - 2.0f); \
        kB##o.y = expf(2.0f * (kB##o.y + ((gi_ == c1 + 1) ? 1.0f : 0.0f)) - 2.0f); \
        kB##o.z = expf(2.0f * (kB##o.z + ((gi_ == c1 + 2) ? 1.0f : 0.0f)) - 2.0f); \
        kB##o.w = expf(2.0f * (kB##o.w + ((gi_ == c1 + 3) ? 1.0f : 0.0f)) - 2.0f); \
        if (a0) *(float4*)(Kb + (size_t)gi_ * NN + c0) = kA##o;              \
        if (a1) *(float4*)(Kb + (size_t)gi_ * NN + c1) = kB##o;              \
    }
    ROWS22(FIN_ROW)
#undef FIN_ROW

    // ---- pass-2 (overflow only): compute rows 176..nrows from hn, store --
    if (nrows > 176) {
        const float* b0p = hnb + (size_t)(c0 + 0) * DD;
        const float* b1p = hnb + (size_t)(c0 + 1) * DD;
        const float* b2p = hnb + (size_t)(c0 + 2) * DD;
        const float* b3p = hnb + (size_t)(c0 + 3) * DD;
        const float* b4p = hnb + (size_t)(c1 + 0) * DD;
        const float* b5p = hnb + (size_t)(c1 + 1) * DD;
        const float* b6p = hnb + (size_t)(c1 + 2) * DD;
        const float* b7p = hnb + (size_t)(c1 + 3) * DD;
        for (int i = 176 + w; i < nrows; i += 8) {
            int gi = r_lo + i;
            const float* rowp = hnb + (size_t)gi * DD;
            float4 accA = {0, 0, 0, 0}, accB = {0, 0, 0, 0};
            for (int kc = 0; kc < DD; kc += 4) {
                float4 a4 = *(const float4*)(rowp + kc);
                float4 p0 = *(const float4*)(b0p + kc);
                float4 p1 = *(const float4*)(b1p + kc);
                float4 p2 = *(const float4*)(b2p + kc);
                float4 p3 = *(const float4*)(b3p + kc);
                float4 q0 = *(const float4*)(b4p + kc);
                float4 q1 = *(const float4*)(b5p + kc);
                float4 q2 = *(const float4*)(b6p + kc);
                float4 q3 = *(const float4*)(b7p + kc);
                accA.x = fmaf(a4.w, p0.w, fmaf(a4.z, p0.z, fmaf(a4.y, p0.y, fmaf(a4.x, p0.x, accA.x))));
                accA.y = fmaf(a4.w, p1.w, fmaf(a4.z, p1.z, fmaf(a4.y, p1.y, fmaf(a4.x, p1.x, accA.y))));
                accA.z = fmaf(a4.w, p2.w, fmaf(a4.z, p2.z, fmaf(a4.y, p2.y, fmaf(a4.x, p2.x, accA.z))));
                accA.w = fmaf(a4.w, p3.w, fmaf(a4.z, p3.z, fmaf(a4.y, p3.y, fmaf(a4.x, p3.x, accA.w))));
                accB.x = fmaf(a4.w, q0.w, fmaf(a4.z, q0.z, fmaf(a4.y, q0.y, fmaf(a4.x, q0.x, accB.x))));
                accB.y = fmaf(a4.w, q1.w, fmaf(a4.z, q1.z, fmaf(a4.y, q1.y, fmaf(a4.x, q1.x, accB.y))));
                accB.z = fmaf(a4.w, q2.w, fmaf(a4.z, q2.z, fmaf(a4.y, q2.y, fmaf(a4.x, q2.x, accB.z))));
                accB.w = fmaf(a4.w, q3.w, fmaf(a4.z, q3.z, fmaf(a4.y, q3.y, fmaf(a4.x, q3.x, accB.w))));
            }
            float4 oA, oB;
            oA.x = expf(2.0f * (accA.x + ((gi == c0 + 0) ? 1.0f : 0.0f)) - 2.0f);
            oA.y = expf(2.0f * (accA.y + ((gi == c0 + 1) ? 1.0f : 0.0f)) - 2.0f);
            oA.z = expf(2.0f * (accA.z + ((gi == c0 + 2) ? 1.0f : 0.0f)) - 2.0f);
            oA.w = expf(2.0f * (accA.w + ((gi == c0 + 3) ? 1.0f : 0.0f)) - 2.0f);
            oB.x = expf(2.0f * (accB.x + ((gi == c1 + 0) ? 1.0f : 0.0f)) - 2.0f);
            oB.y = expf(2.0f * (accB.y + ((gi == c1 + 1) ? 1.0f : 0.0f)) - 2.0f);
            oB.z = expf(2.0f * (accB.z + ((gi == c1 + 2) ? 1.0f : 0.0f)) - 2.0f);
            oB.w = expf(2.0f * (accB.w + ((gi == c1 + 3) ? 1.0f : 0.0f)) - 2.0f);
            if (a0) *(float4*)(Kb + (size_t)gi * NN + c0) = oA;
            if (a1) *(float4*)(Kb + (size_t)gi * NN + c1) = oB;
        }
    }
    __syncthreads();  // fill done; pv reverts to iteration partials

    // ========================= 20 Sinkhorn iterations ======================
    for (int t = 0; t < 20; t++) {
        float4 xv0 = *(const float4*)(xb + c0);
        float4 xv1 = *(const float4*)(xb + c1);
        float4 pa = {0, 0, 0, 0}, pb = {0, 0, 0, 0};

        // ---- phase A (cached): 22 rows/wave entirely from registers ----
#define DOT(o) float d##o = dot8(kA##o, kB##o, xv0, xv1);
        ROWS22(DOT)
#undef DOT
#pragma unroll
        for (int mm = 32; mm; mm >>= 1) {  // 22 interleaved butterfly chains
#define BF(o) d##o += __shfl_xor(d##o, mm);
            ROWS22(BF)
#undef BF
        }
#define RC(o) float uu##o = inv_n / (d##o + 1e-9f);
        ROWS22(RC)
#undef RC
#define ACC_ROW(o)                                                           \
    pa.x = fmaf(kA##o.x, uu##o, pa.x); pa.y = fmaf(kA##o.y, uu##o, pa.y);    \
    pa.z = fmaf(kA##o.z, uu##o, pa.z); pa.w = fmaf(kA##o.w, uu##o, pa.w);    \
    pb.x = fmaf(kB##o.x, uu##o, pb.x); pb.y = fmaf(kB##o.y, uu##o, pb.y);    \
    pb.z = fmaf(kB##o.z, uu##o, pb.z); pb.w = fmaf(kB##o.w, uu##o, pb.w);
        ROWS22(ACC_ROW)
#undef ACC_ROW
        if (t == 19 && l == 0) {
            float* ub = u_buf + (size_t)b * NN + r_lo + w;
#define ST(o) if (w + 8 * (o) < nrows) ub[8 * (o)] = uu##o;
            ROWS22(ST)
#undef ST
        }

        // ---- phase A (streamed): rows >= 176 read from d_out (pass-2 K) --
        for (int i = 176 + w; i < nrows; i += 8) {
            const float* g0 = Kb + (size_t)(r_lo + i) * NN;
            float4 A = {0, 0, 0, 0}, B = {0, 0, 0, 0};
            if (a0) A = *(const float4*)(g0 + c0);
            if (a1) B = *(const float4*)(g0 + c1);
            float d = dot8(A, B, xv0, xv1);
#pragma unroll
            for (int mm = 32; mm; mm >>= 1) d += __shfl_xor(d, mm);
            float uu = inv_n / (d + 1e-9f);
            pa.x = fmaf(A.x, uu, pa.x); pa.y = fmaf(A.y, uu, pa.y);
            pa.z = fmaf(A.z, uu, pa.z); pa.w = fmaf(A.w, uu, pa.w);
            pb.x = fmaf(B.x, uu, pb.x); pb.y = fmaf(B.y, uu, pb.y);
            pb.z = fmaf(B.z, uu, pb.z); pb.w = fmaf(B.w, uu, pb.w);
            if (t == 19 && l == 0) u_buf[(size_t)b * NN + r_lo + i] = uu;
        }

        // ---- phase B: reduce 8 waves' partials (LDS), publish slot + tag ---
        *(float4*)(pv + w * NN + c0) = pa;
        *(float4*)(pv + w * NN + c1) = pb;
        __syncthreads();
        float* slotp = slots + ((size_t)(t & 1) * 512 + g) * SLOT_STRIDE;
        int c = tid;  // one column per thread
        float s0 = pv[c] + pv[NN + c] + pv[2 * NN + c] + pv[3 * NN + c] +
                   pv[4 * NN + c] + pv[5 * NN + c] + pv[6 * NN + c] + pv[7 * NN + c];
        if (S > 1) {
            __hip_atomic_store(slotp + c, s0, __ATOMIC_RELAXED, __HIP_MEMORY_SCOPE_AGENT);
            asm volatile("s_waitcnt vmcnt(0)" ::: "memory");
        }
        __syncthreads();  // all threads' slot stores drained before tag
        if (S > 1 && tid == 0)
            __hip_atomic_store((int*)(slotp + 512), t + 1, __ATOMIC_RELAXED,
                               __HIP_MEMORY_SCOPE_AGENT);
        // ---- barrier: poll the S-1 sibling tags (distinct lines, loads only)
        if (tid < S && tid != q) {
            const int* tagp = (const int*)(slots +
                ((size_t)(t & 1) * 512 + (size_t)(jbase + tid)) * SLOT_STRIDE + 512);
            while (__hip_atomic_load(tagp, __ATOMIC_RELAXED, __HIP_MEMORY_SCOPE_AGENT) != t + 1)
                __builtin_amdgcn_s_sleep(1);
        }
        __syncthreads();

        // ---- phase C: v_c = mu/(colsum+eps); own partial stays in regs ----
        const float* sbase = slots + ((size_t)(t & 1) * 512) * SLOT_STRIDE;
        float t0 = s0;
        for (int s = 1; s < S; s++) {
            int k = q + s; if (k >= S) k -= S;  // stagger sibling order
            t0 += __hip_atomic_load(sbase + (size_t)(jbase + k) * SLOT_STRIDE + c,
                                    __ATOMIC_RELAXED, __HIP_MEMORY_SCOPE_AGENT);
        }
        float v0 = (c < len) ? (inv_n / (t0 + 1e-9f)) : 0.0f;
        if (t < 19) {
            xb[c] = v0;
        } else if (c >= r_lo && c < r_lo + nrows) {
            v_buf[(size_t)b * NN + c] = v0;  // owner writes final v
        }
        __syncthreads();
    }
}

// ---------------- kernel 4: fused epilogue, in-place on d_out -------------
__global__ __launch_bounds__(256) void epi_kernel(float* __restrict__ io,
                                                  const float* __restrict__ u,
                                                  const float* __restrict__ v,
                                                  const int* __restrict__ lengths) {
    const float E5 = 0.006737946999085467f;  // exp(-5)
    size_t idx = (size_t)blockIdx.x * 256 + threadIdx.x;  // float4 index
    int b = (int)(idx >> 16);
    int r = (int)(idx >> 7) & (NN - 1);
    int c4 = ((int)idx & 127) << 2;
    int len = max(lengths[b], 1);
    float4 o;
    if (r >= len || c4 >= len) {
        o.x = E5; o.y = E5; o.z = E5; o.w = E5;
        ((float4*)io)[idx] = o;
        return;
    }
    float4 k = ((float4*)io)[idx];
    float ui = u[(size_t)b * NN + r];
    float4 vv = *(const float4*)(v + (size_t)b * NN + c4);
    float t = (float)len * ui;
    float kv[4] = {k.x, k.y, k.z, k.w};
    float vj[4] = {vv.x, vv.y, vv.z, vv.w};
    float ov[4];
#pragma unroll
    for (int c = 0; c < 4; c++) {
        float Kc = kv[c];
        float P = t * Kc * vj[c];
        bool valid = (c4 + c) < len;
        if (valid && P > 0.1f) {
            float x = 2.5f * logf(Kc);  // == 5*sim - 5
            ov[c] = (x > 0.0f) ? (x + 1.0f) : expf(x);
        } else {
            ov[c] = E5;
        }
    }
    o.x = ov[0]; o.y = ov[1]; o.z = ov[2]; o.w = ov[3];
    ((float4*)io)[idx] = o;
}

extern "C" void kernel_launch(void* const* d_in, const int* in_sizes, int n_in,
                              void* d_out, int out_size, void* d_ws, size_t ws_size,
                              hipStream_t stream) {
    const float* h = (const float*)d_in[0];
    const float* W0 = (const float*)d_in[1];
    const float* W1 = (const float*)d_in[2];
    const int* lengths = (const int*)d_in[3];
    float* K = (float*)d_out;  // [B,N,N]: K rows written by coop_sink's fill

    char* ws = (char*)d_ws;
    float* hn = (float*)ws;                                   // 33.5 MB
    size_t off = (size_t)BB * NN * DD * 4;
    float* u = (float*)(ws + off);     off += (size_t)BB * NN * 4;               // 256 KB
    float* v = (float*)(ws + off);     off += (size_t)BB * NN * 4;               // 256 KB
    float* slots = (float*)(ws + off); off += (size_t)2 * 512 * SLOT_STRIDE * 4; // 2.2 MB

    hn_kernel<<<BB * NN / 4, 256, 0, stream>>>(h, W0, W1, hn);

    // sim_kernel DELETED: coop_sink computes K from hn in its fill phase,
    // writes K rows to d_out (epi unchanged), iterates from registers.
    coop_sink<<<256, 512, 0, stream>>>(hn, K, u, v, lengths, slots);

    epi_kernel<<<(unsigned)((size_t)BB * NN * NN / 4 / 256), 256, 0, stream>>>(K, u, v, lengths);
}

// Round 8
// 391.264 us; speedup vs baseline: 1.3451x; 1.3451x over previous
//
#include <hip/hip_runtime.h>

#define BB 128
#define NN 512
#define DD 128
#define SLOT_STRIDE 544  // 512 data floats + tag int at [512] + pad (2176 B)

// ---------------- kernel 1: h -> normalized hn ----------------
__global__ __launch_bounds__(256) void hn_kernel(const float* __restrict__ h,
                                                 const float* __restrict__ W0,
                                                 const float* __restrict__ W1,
                                                 float* __restrict__ hn) {
    int wave = (int)((blockIdx.x * blockDim.x + threadIdx.x) >> 6);  // 0..B*N-1
    int lane = threadIdx.x & 63;
    const float2* h2 = (const float2*)(h + (size_t)wave * DD);
    float2 w0 = ((const float2*)W0)[lane];
    float2 w1 = ((const float2*)W1)[lane];
    float2 x = h2[lane];
    float p0 = fmaxf(x.x * w0.x, 0.0f) * w1.x;
    float p1 = fmaxf(x.y * w0.y, 0.0f) * w1.y;
    float ss = p0 * p0 + p1 * p1;
#pragma unroll
    for (int m = 32; m; m >>= 1) ss += __shfl_xor(ss, m);
    float inv = 1.0f / (sqrtf(ss) + 1e-12f);
    float2 o;
    o.x = p0 * inv;
    o.y = p1 * inv;
    ((float2*)(hn + (size_t)wave * DD))[lane] = o;
}

// ---------------- kernel 2: K = exp(2*(hn hn^T + eye) - 2), persistent -----
#define KC 32
__global__ __launch_bounds__(256) void sim_kernel(const float* __restrict__ hn,
                                                  const int* __restrict__ lengths,
                                                  float* __restrict__ K) {
    __shared__ float As[KC][132];
    __shared__ float Bs[KC][132];
    __shared__ int pre[BB + 1];  // prefix sum of per-batch tile counts
    int tid = threadIdx.x;
    if (tid == 0) {
        int acc = 0;
        for (int b = 0; b < BB; b++) {
            pre[b] = acc;
            int len = max(lengths[b], 1);
            int nt = (len + 127) >> 7;
            acc += nt * nt;
        }
        pre[BB] = acc;
    }
    __syncthreads();
    int total = pre[BB];

    int lr = tid >> 3;
    int lk = (tid & 7) << 2;
    int tx = tid & 15, ty = tid >> 4;

    for (int t = blockIdx.x; t < total; t += gridDim.x) {
        int lo = 0, hi = BB;
        while (lo + 1 < hi) {
            int mid = (lo + hi) >> 1;
            if (pre[mid] <= t) lo = mid; else hi = mid;
        }
        int b = lo;
        int local = t - pre[b];
        int len = max(lengths[b], 1);
        int nt = (len + 127) >> 7;
        int ti = local / nt;
        int tj = local - ti * nt;
        int r0 = ti << 7, c0 = tj << 7;
        const float* base = hn + (size_t)b * NN * DD;
        float acc[8][8] = {};

        for (int kc = 0; kc < DD; kc += KC) {
#pragma unroll
            for (int rr = 0; rr < 128; rr += 32) {
                float4 a = *(const float4*)(base + (size_t)(r0 + lr + rr) * DD + kc + lk);
                As[lk + 0][lr + rr] = a.x; As[lk + 1][lr + rr] = a.y;
                As[lk + 2][lr + rr] = a.z; As[lk + 3][lr + rr] = a.w;
                float4 bb = *(const float4*)(base + (size_t)(c0 + lr + rr) * DD + kc + lk);
                Bs[lk + 0][lr + rr] = bb.x; Bs[lk + 1][lr + rr] = bb.y;
                Bs[lk + 2][lr + rr] = bb.z; Bs[lk + 3][lr + rr] = bb.w;
            }
            __syncthreads();
#pragma unroll
            for (int kk = 0; kk < KC; kk++) {
                float4 a0 = *(const float4*)&As[kk][ty * 8];
                float4 a1 = *(const float4*)&As[kk][ty * 8 + 4];
                float4 b0 = *(const float4*)&Bs[kk][tx * 4];
                float4 b1 = *(const float4*)&Bs[kk][64 + tx * 4];
                float ar[8] = {a0.x, a0.y, a0.z, a0.w, a1.x, a1.y, a1.z, a1.w};
                float bc[8] = {b0.x, b0.y, b0.z, b0.w, b1.x, b1.y, b1.z, b1.w};
#pragma unroll
                for (int r = 0; r < 8; r++)
#pragma unroll
                    for (int c = 0; c < 8; c++)
                        acc[r][c] = fmaf(ar[r], bc[c], acc[r][c]);
            }
            __syncthreads();
        }
        float* out = K + (size_t)b * NN * NN;
#pragma unroll
        for (int r = 0; r < 8; r++) {
            int i = r0 + ty * 8 + r;
            if (i >= len) continue;
#pragma unroll
            for (int cg = 0; cg < 2; cg++) {
                int j0 = c0 + cg * 64 + tx * 4;
                if (j0 >= len) continue;
                float vv[4];
#pragma unroll
                for (int c = 0; c < 4; c++) {
                    float s = acc[r][cg * 4 + c] + ((i == j0 + c) ? 1.0f : 0.0f);
                    vv[c] = expf(2.0f * s - 2.0f);
                }
                float4 o;
                o.x = vv[0]; o.y = vv[1]; o.z = vv[2]; o.w = vv[3];
                *(float4*)(out + (size_t)i * NN + j0) = o;
            }
        }
    }
}

// ---------------- kernel 2b: E5-pad all rows >= len (disjoint from sim) ---
__global__ __launch_bounds__(256) void pad_kernel(float* __restrict__ io,
                                                  const int* __restrict__ lengths) {
    const float E5 = 0.006737946999085467f;  // exp(-5)
    size_t idx = (size_t)blockIdx.x * 256 + threadIdx.x;  // float4 index
    int b = (int)(idx >> 16);
    int r = (int)(idx >> 7) & (NN - 1);
    int len = max(lengths[b], 1);
    if (r < len) return;  // wave-coherent (a row spans whole waves)
    float4 o;
    o.x = E5; o.y = E5; o.z = E5; o.w = E5;
    ((float4*)io)[idx] = o;
}

__device__ __forceinline__ float dot8(float4 A, float4 B, float4 x0, float4 x1) {
    float d = fmaf(A.x, x0.x, fmaf(A.y, x0.y, fmaf(A.z, x0.z, A.w * x0.w)));
    return fmaf(B.x, x1.x, fmaf(B.y, x1.y, fmaf(B.z, x1.z, fmaf(B.w, x1.w, d))));
}

// epilogue element: bitwise-identical to old epi_kernel's per-element math
__device__ __forceinline__ float outf(float tt, float Kc, float vj, bool valid) {
    const float E5 = 0.006737946999085467f;
    float P = tt * Kc * vj;  // == (len*u)*K*v, left-assoc like epi
    if (valid && P > 0.1f) {
        float x = 2.5f * logf(Kc);  // == 5*sim - 5
        return (x > 0.0f) ? (x + 1.0f) : expf(x);
    }
    return E5;
}

// ---------------- persistent Sinkhorn + fused epilogue --------------------
// R23 post-mortem of R22: fused sim-fill cost 212us because the K cache
// lives in AGPRs (VGPR_Count=128 < 176 cache regs) and the fill GEMM
// ACCUMULATES into it -> every fmaf = accvgpr_read+fma+accvgpr_write (3x),
// plus 1.5M LDS bank conflicts. Fill reverted to R21 (read K from sim).
// This round fuses the EPILOGUE instead: at t=19 coop holds K (regs, only
// READ -> AGPR-friendly), u (uu_o lane-uniform), v (phase C computes every
// column). Last iteration is PEELED out of the loop (R18 lesson: no
// conditionals in the hot loop; also drops the t==19 checks), phase C
// writes v to xb, then the block writes final output rows from registers,
// replicating epi's op order exactly. Rows >= len padded by pad_kernel
// (disjoint region). u_buf/v_buf/epi_kernel deleted. Overflow rows (rare)
// stash u in LDS (uS) and epilogue from d_out. Exchange protocol unchanged.
#define ROWS22(X) X(0) X(1) X(2) X(3) X(4) X(5) X(6) X(7) X(8) X(9) X(10) \
    X(11) X(12) X(13) X(14) X(15) X(16) X(17) X(18) X(19) X(20) X(21)

__global__ __launch_bounds__(512, 2) void coop_sink(float* __restrict__ K,
                                                    const int* __restrict__ lengths,
                                                    float* __restrict__ slots) {
    __shared__ float xb[NN];      // current multiplier vector (v)
    __shared__ float pv[8 * NN];  // per-wave column partials (16 KB)
    __shared__ float uS[NN];      // streamed-row u (overflow case only)
    __shared__ int Sh[BB], Pre[BB];

    int g = blockIdx.x;
    int tid = threadIdx.x;

    // ---- deterministic GLOBAL schedule: S_b = ceil(len/176), sum <= 256 ---
    if (tid == 0) {
        int need[BB]; int ssum = 0;
        for (int m = 0; m < BB; m++) {
            int L = max(lengths[m], 1);
            need[m] = (L + 175) / 176;  // 1..3
            ssum += need[m];
        }
        while (ssum > 256) {  // rare: shrink the largest (first on tie)
            int best = 0, bv = need[0];
            for (int m = 1; m < BB; m++)
                if (need[m] > bv) { bv = need[m]; best = m; }
            need[best]--; ssum--;
        }
        int acc = 0;
        for (int m = 0; m < BB; m++) { Pre[m] = acc; Sh[m] = need[m]; acc += need[m]; }
    }
    __syncthreads();

    int m = -1;
    for (int mm = 0; mm < BB; mm++)
        if (g >= Pre[mm] && g < Pre[mm] + Sh[mm]) { m = mm; break; }
    if (m < 0) return;  // surplus block: idle
    int b = m;                  // batch
    int jbase = Pre[m];
    int q = g - jbase;          // slice within batch
    int S = Sh[m];              // slices for this batch (<=3)

    int len = max(lengths[b], 1);
    int len4 = (len + 3) & ~3;
    int rpq = (len + S - 1) / S;
    int r_lo = q * rpq;
    int nrows = min(len - r_lo, rpq);
    if (nrows < 0) nrows = 0;
    float inv_n = 1.0f / (float)len;

    int w = tid >> 6, l = tid & 63;
    int c0 = 4 * l, c1 = 256 + 4 * l;
    bool a0 = c0 < len4, a1 = c1 < len4;
    float* Kb = K + (size_t)b * NN * NN;

    xb[tid] = (tid < len) ? 1.0f : 0.0f;

    // ---- register-resident K slice: rows w+8o (o<22), named scalars -------
#define DECL(o) float4 kA##o = {0,0,0,0}, kB##o = {0,0,0,0};
    ROWS22(DECL)
#undef DECL
#define FILL_ROW(o)                                                          \
    {                                                                        \
        int i_ = w + 8 * (o);                                                \
        if (i_ < nrows) {                                                    \
            const float* g0_ = Kb + (size_t)(r_lo + i_) * NN;                \
            if (a0) kA##o = *(const float4*)(g0_ + c0);                      \
            if (a1) kB##o = *(const float4*)(g0_ + c1);                      \
        }                                                                    \
    }
    ROWS22(FILL_ROW)
#undef FILL_ROW

    __syncthreads();

    // phase-A / B / C bodies as macros so the peeled last iteration reuses
    // the exact same code (bitwise-identical op order).
#define PHASE_A_CACHED                                                       \
    ROWS22(DOT)                                                              \
    _Pragma("unroll")                                                        \
    for (int mm2 = 32; mm2; mm2 >>= 1) { ROWS22(BF2) }                       \
    ROWS22(RC) ROWS22(ACC_ROW)

#define DOT(o) float d##o = dot8(kA##o, kB##o, xv0, xv1);
#define BF2(o) d##o += __shfl_xor(d##o, mm2);
#define RC(o) float uu##o = inv_n / (d##o + 1e-9f);
#define ACC_ROW(o)                                                           \
    pa.x = fmaf(kA##o.x, uu##o, pa.x); pa.y = fmaf(kA##o.y, uu##o, pa.y);    \
    pa.z = fmaf(kA##o.z, uu##o, pa.z); pa.w = fmaf(kA##o.w, uu##o, pa.w);    \
    pb.x = fmaf(kB##o.x, uu##o, pb.x); pb.y = fmaf(kB##o.y, uu##o, pb.y);    \
    pb.z = fmaf(kB##o.z, uu##o, pb.z); pb.w = fmaf(kB##o.w, uu##o, pb.w);

    // ================= iterations t = 0..18 (hot loop, no conditionals) ====
    for (int t = 0; t < 19; t++) {
        float4 xv0 = *(const float4*)(xb + c0);
        float4 xv1 = *(const float4*)(xb + c1);
        float4 pa = {0, 0, 0, 0}, pb = {0, 0, 0, 0};

        PHASE_A_CACHED

        for (int i = 176 + w; i < nrows; i += 8) {  // rare overflow stream
            const float* g0 = Kb + (size_t)(r_lo + i) * NN;
            float4 A = {0, 0, 0, 0}, B = {0, 0, 0, 0};
            if (a0) A = *(const float4*)(g0 + c0);
            if (a1) B = *(const float4*)(g0 + c1);
            float d = dot8(A, B, xv0, xv1);
#pragma unroll
            for (int mm2 = 32; mm2; mm2 >>= 1) d += __shfl_xor(d, mm2);
            float uu = inv_n / (d + 1e-9f);
            pa.x = fmaf(A.x, uu, pa.x); pa.y = fmaf(A.y, uu, pa.y);
            pa.z = fmaf(A.z, uu, pa.z); pa.w = fmaf(A.w, uu, pa.w);
            pb.x = fmaf(B.x, uu, pb.x); pb.y = fmaf(B.y, uu, pb.y);
            pb.z = fmaf(B.z, uu, pb.z); pb.w = fmaf(B.w, uu, pb.w);
        }

        // phase B: LDS reduce + publish slot + tag
        *(float4*)(pv + w * NN + c0) = pa;
        *(float4*)(pv + w * NN + c1) = pb;
        __syncthreads();
        float* slotp = slots + ((size_t)(t & 1) * 512 + g) * SLOT_STRIDE;
        int c = tid;
        float s0 = pv[c] + pv[NN + c] + pv[2 * NN + c] + pv[3 * NN + c] +
                   pv[4 * NN + c] + pv[5 * NN + c] + pv[6 * NN + c] + pv[7 * NN + c];
        if (S > 1) {
            __hip_atomic_store(slotp + c, s0, __ATOMIC_RELAXED, __HIP_MEMORY_SCOPE_AGENT);
            asm volatile("s_waitcnt vmcnt(0)" ::: "memory");
        }
        __syncthreads();
        if (S > 1 && tid == 0)
            __hip_atomic_store((int*)(slotp + 512), t + 1, __ATOMIC_RELAXED,
                               __HIP_MEMORY_SCOPE_AGENT);
        if (tid < S && tid != q) {
            const int* tagp = (const int*)(slots +
                ((size_t)(t & 1) * 512 + (size_t)(jbase + tid)) * SLOT_STRIDE + 512);
            while (__hip_atomic_load(tagp, __ATOMIC_RELAXED, __HIP_MEMORY_SCOPE_AGENT) != t + 1)
                __builtin_amdgcn_s_sleep(1);
        }
        __syncthreads();

        // phase C
        const float* sbase = slots + ((size_t)(t & 1) * 512) * SLOT_STRIDE;
        float t0 = s0;
        for (int s = 1; s < S; s++) {
            int k = q + s; if (k >= S) k -= S;
            t0 += __hip_atomic_load(sbase + (size_t)(jbase + k) * SLOT_STRIDE + c,
                                    __ATOMIC_RELAXED, __HIP_MEMORY_SCOPE_AGENT);
        }
        float v0 = (c < len) ? (inv_n / (t0 + 1e-9f)) : 0.0f;
        xb[c] = v0;
        __syncthreads();
    }

    // ================= peeled final iteration (t = 19) + fused epilogue ====
    {
        float4 xv0 = *(const float4*)(xb + c0);
        float4 xv1 = *(const float4*)(xb + c1);
        float4 pa = {0, 0, 0, 0}, pb = {0, 0, 0, 0};

        PHASE_A_CACHED

        for (int i = 176 + w; i < nrows; i += 8) {  // overflow: keep uu in uS
            const float* g0 = Kb + (size_t)(r_lo + i) * NN;
            float4 A = {0, 0, 0, 0}, B = {0, 0, 0, 0};
            if (a0) A = *(const float4*)(g0 + c0);
            if (a1) B = *(const float4*)(g0 + c1);
            float d = dot8(A, B, xv0, xv1);
#pragma unroll
            for (int mm2 = 32; mm2; mm2 >>= 1) d += __shfl_xor(d, mm2);
            float uu = inv_n / (d + 1e-9f);
            pa.x = fmaf(A.x, uu, pa.x); pa.y = fmaf(A.y, uu, pa.y);
            pa.z = fmaf(A.z, uu, pa.z); pa.w = fmaf(A.w, uu, pa.w);
            pb.x = fmaf(B.x, uu, pb.x); pb.y = fmaf(B.y, uu, pb.y);
            pb.z = fmaf(B.z, uu, pb.z); pb.w = fmaf(B.w, uu, pb.w);
            uS[i] = uu;  // lane-uniform; barriers below order the read
        }

        // phase B (t=19: parity 1, tag 20)
        *(float4*)(pv + w * NN + c0) = pa;
        *(float4*)(pv + w * NN + c1) = pb;
        __syncthreads();
        float* slotp = slots + ((size_t)1 * 512 + g) * SLOT_STRIDE;
        int c = tid;
        float s0 = pv[c] + pv[NN + c] + pv[2 * NN + c] + pv[3 * NN + c] +
                   pv[4 * NN + c] + pv[5 * NN + c] + pv[6 * NN + c] + pv[7 * NN + c];
        if (S > 1) {
            __hip_atomic_store(slotp + c, s0, __ATOMIC_RELAXED, __HIP_MEMORY_SCOPE_AGENT);
            asm volatile("s_waitcnt vmcnt(0)" ::: "memory");
        }
        __syncthreads();
        if (S > 1 && tid == 0)
            __hip_atomic_store((int*)(slotp + 512), 20, __ATOMIC_RELAXED,
                               __HIP_MEMORY_SCOPE_AGENT);
        if (tid < S && tid != q) {
            const int* tagp = (const int*)(slots +
                ((size_t)1 * 512 + (size_t)(jbase + tid)) * SLOT_STRIDE + 512);
            while (__hip_atomic_load(tagp, __ATOMIC_RELAXED, __HIP_MEMORY_SCOPE_AGENT) != 20)
                __builtin_amdgcn_s_sleep(1);
        }
        __syncthreads();

        // phase C -> final v into xb
        const float* sbase = slots + ((size_t)1 * 512) * SLOT_STRIDE;
        float t0 = s0;
        for (int s = 1; s < S; s++) {
            int k = q + s; if (k >= S) k -= S;
            t0 += __hip_atomic_load(sbase + (size_t)(jbase + k) * SLOT_STRIDE + c,
                                    __ATOMIC_RELAXED, __HIP_MEMORY_SCOPE_AGENT);
        }
        float v0 = (c < len) ? (inv_n / (t0 + 1e-9f)) : 0.0f;
        xb[c] = v0;
        __syncthreads();

        // ---- fused epilogue: out = f(len*u*K*v) from registers ----
        float4 w0v = *(const float4*)(xb + c0);
        float4 w1v = *(const float4*)(xb + c1);
#define EPI_ROW(o)                                                           \
        if (w + 8 * (o) < nrows) {                                           \
            int gi_ = r_lo + w + 8 * (o);                                    \
            float tt_ = (float)len * uu##o;                                  \
            float4 oA_, oB_;                                                 \
            oA_.x = outf(tt_, kA##o.x, w0v.x, c0 + 0 < len);                 \
            oA_.y = outf(tt_, kA##o.y, w0v.y, c0 + 1 < len);                 \
            oA_.z = outf(tt_, kA##o.z, w0v.z, c0 + 2 < len);                 \
            oA_.w = outf(tt_, kA##o.w, w0v.w, c0 + 3 < len);                 \
            oB_.x = outf(tt_, kB##o.x, w1v.x, c1 + 0 < len);                 \
            oB_.y = outf(tt_, kB##o.y, w1v.y, c1 + 1 < len);                 \
            oB_.z = outf(tt_, kB##o.z, w1v.z, c1 + 2 < len);                 \
            oB_.w = outf(tt_, kB##o.w, w1v.w, c1 + 3 < len);                 \
            *(float4*)(Kb + (size_t)gi_ * NN + c0) = oA_;                    \
            *(float4*)(Kb + (size_t)gi_ * NN + c1) = oB_;                    \
        }
        ROWS22(EPI_ROW)
#undef EPI_ROW

        // streamed epilogue (overflow rows): K from d_out, u from uS
        for (int i = 176 + w; i < nrows; i += 8) {
            int gi = r_lo + i;
            float tt = (float)len * uS[i];
            const float* g0 = Kb + (size_t)gi * NN;
            float4 A = {0, 0, 0, 0}, B = {0, 0, 0, 0};
            if (a0) A = *(const float4*)(g0 + c0);
            if (a1) B = *(const float4*)(g0 + c1);
            float4 oA, oB;
            oA.x = outf(tt, A.x, w0v.x, c0 + 0 < len);
            oA.y = outf(tt, A.y, w0v.y, c0 + 1 < len);
            oA.z = outf(tt, A.z, w0v.z, c0 + 2 < len);
            oA.w = outf(tt, A.w, w0v.w, c0 + 3 < len);
            oB.x = outf(tt, B.x, w1v.x, c1 + 0 < len);
            oB.y = outf(tt, B.y, w1v.y, c1 + 1 < len);
            oB.z = outf(tt, B.z, w1v.z, c1 + 2 < len);
            oB.w = outf(tt, B.w, w1v.w, c1 + 3 < len);
            *(float4*)(Kb + (size_t)gi * NN + c0) = oA;
            *(float4*)(Kb + (size_t)gi * NN + c1) = oB;
        }
    }
#undef DOT
#undef BF2
#undef RC
#undef ACC_ROW
#undef PHASE_A_CACHED
}

extern "C" void kernel_launch(void* const* d_in, const int* in_sizes, int n_in,
                              void* d_out, int out_size, void* d_ws, size_t ws_size,
                              hipStream_t stream) {
    const float* h = (const float*)d_in[0];
    const float* W0 = (const float*)d_in[1];
    const float* W1 = (const float*)d_in[2];
    const int* lengths = (const int*)d_in[3];
    float* K = (float*)d_out;  // [B,N,N]: K from sim, overwritten with output

    char* ws = (char*)d_ws;
    float* hn = (float*)ws;                                   // 33.5 MB
    size_t off = (size_t)BB * NN * DD * 4;
    float* slots = (float*)(ws + off); off += (size_t)2 * 512 * SLOT_STRIDE * 4; // 2.2 MB

    hn_kernel<<<BB * NN / 4, 256, 0, stream>>>(h, W0, W1, hn);
    sim_kernel<<<1024, 256, 0, stream>>>(hn, lengths, K);
    // pad rows >= len with E5 (disjoint from sim's writes and coop's rows)
    pad_kernel<<<(unsigned)((size_t)BB * NN * NN / 4 / 256), 256, 0, stream>>>(K, lengths);

    // 256 blocks x 512 thr, 1 block/CU; K cached in registers; epilogue fused.
    coop_sink<<<256, 512, 0, stream>>>(K, lengths, slots);
}

// Round 9
// 362.570 us; speedup vs baseline: 1.4516x; 1.0791x over previous
//
#include <hip/hip_runtime.h>

#define BB 128
#define NN 512
#define DD 128

// ---------------- kernel 1: h -> normalized hn ----------------
__global__ __launch_bounds__(256) void hn_kernel(const float* __restrict__ h,
                                                 const float* __restrict__ W0,
                                                 const float* __restrict__ W1,
                                                 float* __restrict__ hn) {
    int wave = (int)((blockIdx.x * blockDim.x + threadIdx.x) >> 6);  // 0..B*N-1
    int lane = threadIdx.x & 63;
    const float2* h2 = (const float2*)(h + (size_t)wave * DD);
    float2 w0 = ((const float2*)W0)[lane];
    float2 w1 = ((const float2*)W1)[lane];
    float2 x = h2[lane];
    float p0 = fmaxf(x.x * w0.x, 0.0f) * w1.x;
    float p1 = fmaxf(x.y * w0.y, 0.0f) * w1.y;
    float ss = p0 * p0 + p1 * p1;
#pragma unroll
    for (int m = 32; m; m >>= 1) ss += __shfl_xor(ss, m);
    float inv = 1.0f / (sqrtf(ss) + 1e-12f);
    float2 o;
    o.x = p0 * inv;
    o.y = p1 * inv;
    ((float2*)(hn + (size_t)wave * DD))[lane] = o;
}

// ---------------- kernel 2: K = exp(2*(hn hn^T + eye) - 2), persistent -----
#define KC 32
__global__ __launch_bounds__(256) void sim_kernel(const float* __restrict__ hn,
                                                  const int* __restrict__ lengths,
                                                  float* __restrict__ K) {
    __shared__ float As[KC][132];
    __shared__ float Bs[KC][132];
    __shared__ int pre[BB + 1];  // prefix sum of per-batch tile counts
    int tid = threadIdx.x;
    if (tid == 0) {
        int acc = 0;
        for (int b = 0; b < BB; b++) {
            pre[b] = acc;
            int len = max(lengths[b], 1);
            int nt = (len + 127) >> 7;
            acc += nt * nt;
        }
        pre[BB] = acc;
    }
    __syncthreads();
    int total = pre[BB];

    int lr = tid >> 3;
    int lk = (tid & 7) << 2;
    int tx = tid & 15, ty = tid >> 4;

    for (int t = blockIdx.x; t < total; t += gridDim.x) {
        int lo = 0, hi = BB;
        while (lo + 1 < hi) {
            int mid = (lo + hi) >> 1;
            if (pre[mid] <= t) lo = mid; else hi = mid;
        }
        int b = lo;
        int local = t - pre[b];
        int len = max(lengths[b], 1);
        int nt = (len + 127) >> 7;
        int ti = local / nt;
        int tj = local - ti * nt;
        int r0 = ti << 7, c0 = tj << 7;
        const float* base = hn + (size_t)b * NN * DD;
        float acc[8][8] = {};

        for (int kc = 0; kc < DD; kc += KC) {
#pragma unroll
            for (int rr = 0; rr < 128; rr += 32) {
                float4 a = *(const float4*)(base + (size_t)(r0 + lr + rr) * DD + kc + lk);
                As[lk + 0][lr + rr] = a.x; As[lk + 1][lr + rr] = a.y;
                As[lk + 2][lr + rr] = a.z; As[lk + 3][lr + rr] = a.w;
                float4 bb = *(const float4*)(base + (size_t)(c0 + lr + rr) * DD + kc + lk);
                Bs[lk + 0][lr + rr] = bb.x; Bs[lk + 1][lr + rr] = bb.y;
                Bs[lk + 2][lr + rr] = bb.z; Bs[lk + 3][lr + rr] = bb.w;
            }
            __syncthreads();
#pragma unroll
            for (int kk = 0; kk < KC; kk++) {
                float4 a0 = *(const float4*)&As[kk][ty * 8];
                float4 a1 = *(const float4*)&As[kk][ty * 8 + 4];
                float4 b0 = *(const float4*)&Bs[kk][tx * 4];
                float4 b1 = *(const float4*)&Bs[kk][64 + tx * 4];
                float ar[8] = {a0.x, a0.y, a0.z, a0.w, a1.x, a1.y, a1.z, a1.w};
                float bc[8] = {b0.x, b0.y, b0.z, b0.w, b1.x, b1.y, b1.z, b1.w};
#pragma unroll
                for (int r = 0; r < 8; r++)
#pragma unroll
                    for (int c = 0; c < 8; c++)
                        acc[r][c] = fmaf(ar[r], bc[c], acc[r][c]);
            }
            __syncthreads();
        }
        float* out = K + (size_t)b * NN * NN;
#pragma unroll
        for (int r = 0; r < 8; r++) {
            int i = r0 + ty * 8 + r;
            if (i >= len) continue;
#pragma unroll
            for (int cg = 0; cg < 2; cg++) {
                int j0 = c0 + cg * 64 + tx * 4;
                if (j0 >= len) continue;
                float vv[4];
#pragma unroll
                for (int c = 0; c < 4; c++) {
                    float s = acc[r][cg * 4 + c] + ((i == j0 + c) ? 1.0f : 0.0f);
                    vv[c] = expf(2.0f * s - 2.0f);
                }
                float4 o;
                o.x = vv[0]; o.y = vv[1]; o.z = vv[2]; o.w = vv[3];
                *(float4*)(out + (size_t)i * NN + j0) = o;
            }
        }
    }
}

__device__ __forceinline__ float dot8(float4 A, float4 B, float4 x0, float4 x1) {
    float d = fmaf(A.x, x0.x, fmaf(A.y, x0.y, fmaf(A.z, x0.z, A.w * x0.w)));
    return fmaf(B.x, x1.x, fmaf(B.y, x1.y, fmaf(B.z, x1.z, fmaf(B.w, x1.w, d))));
}

// ---------------- persistent Sinkhorn: 20 iters, K register-resident ------
// R24 = R21 (proven best: coop 148us, total 377.8) with ONE change: the
// exchange. R21's serial chain per iter = slot store + vmcnt(0) drain +
// sync + tid0 tag store + tag-poll RT + sync + data-read RT = ~3 agent-
// scope round trips + 4 barriers. R23's fused-epilogue detour proved the
// iter loop itself is untouched by everything else. New protocol: each
// thread publishes (tag<<32 | float_bits(partial)) as ONE 8-byte relaxed
// agent atomic per column; consumers poll their own column of each
// sibling until the tag half == t+1 and take the value half from the
// same load. 1 RT instead of 3; drain/tag/2-of-4 barriers deleted.
// Safety: identical 2-parity induction as the proven tag protocol (a
// block reaches its parity-p overwrite at t+2 only after all siblings
// completed phase C of t, because its t+1 poll requires their t+1 B-
// stores which follow their C_t + local barrier). Cross-rep staleness:
// parity-p stale tags (19/20) are overwritten at t=0/1 before any later
// poll can match them. Value bits pass through the u64 unchanged and the
// staggered sibling sum order is identical -> bitwise-identical output.
#define ROWS22(X) X(0) X(1) X(2) X(3) X(4) X(5) X(6) X(7) X(8) X(9) X(10) \
    X(11) X(12) X(13) X(14) X(15) X(16) X(17) X(18) X(19) X(20) X(21)

__global__ __launch_bounds__(512, 2) void coop_sink(const float* __restrict__ K,
                                                    float* __restrict__ u_buf,
                                                    float* __restrict__ v_buf,
                                                    const int* __restrict__ lengths,
                                                    unsigned long long* __restrict__ slots64) {
    __shared__ float xb[NN];      // current multiplier vector (v)
    __shared__ float pv[8 * NN];  // per-wave column partials (16 KB)
    __shared__ int Sh[BB], Pre[BB];

    int g = blockIdx.x;
    int tid = threadIdx.x;

    // ---- deterministic GLOBAL schedule: S_b = ceil(len/176), sum <= 256 ---
    if (tid == 0) {
        int need[BB]; int ssum = 0;
        for (int m = 0; m < BB; m++) {
            int L = max(lengths[m], 1);
            need[m] = (L + 175) / 176;  // 1..3
            ssum += need[m];
        }
        while (ssum > 256) {  // rare: shrink the largest (first on tie)
            int best = 0, bv = need[0];
            for (int m = 1; m < BB; m++)
                if (need[m] > bv) { bv = need[m]; best = m; }
            need[best]--; ssum--;
        }
        int acc = 0;
        for (int m = 0; m < BB; m++) { Pre[m] = acc; Sh[m] = need[m]; acc += need[m]; }
    }
    __syncthreads();

    int m = -1;
    for (int mm = 0; mm < BB; mm++)
        if (g >= Pre[mm] && g < Pre[mm] + Sh[mm]) { m = mm; break; }
    if (m < 0) return;  // surplus block: idle
    int b = m;                  // batch
    int jbase = Pre[m];
    int q = g - jbase;          // slice within batch
    int S = Sh[m];              // slices for this batch (<=3)

    int len = max(lengths[b], 1);
    int len4 = (len + 3) & ~3;
    int rpq = (len + S - 1) / S;
    int r_lo = q * rpq;
    int nrows = min(len - r_lo, rpq);
    if (nrows < 0) nrows = 0;
    float inv_n = 1.0f / (float)len;

    int w = tid >> 6, l = tid & 63;
    int c0 = 4 * l, c1 = 256 + 4 * l;
    bool a0 = c0 < len4, a1 = c1 < len4;
    const float* Kb = K + (size_t)b * NN * NN;

    xb[tid] = (tid < len) ? 1.0f : 0.0f;

    // ---- register-resident K slice: rows w+8o (o<22), named scalars -------
#define DECL(o) float4 kA##o = {0,0,0,0}, kB##o = {0,0,0,0};
    ROWS22(DECL)
#undef DECL
#define FILL_ROW(o)                                                          \
    {                                                                        \
        int i_ = w + 8 * (o);                                                \
        if (i_ < nrows) {                                                    \
            const float* g0_ = Kb + (size_t)(r_lo + i_) * NN;                \
            if (a0) kA##o = *(const float4*)(g0_ + c0);                      \
            if (a1) kB##o = *(const float4*)(g0_ + c1);                      \
        }                                                                    \
    }
    ROWS22(FILL_ROW)
#undef FILL_ROW

    __syncthreads();

    for (int t = 0; t < 20; t++) {
        float4 xv0 = *(const float4*)(xb + c0);
        float4 xv1 = *(const float4*)(xb + c1);
        float4 pa = {0, 0, 0, 0}, pb = {0, 0, 0, 0};

        // ---- phase A (cached): 22 rows/wave entirely from registers ----
#define DOT(o) float d##o = dot8(kA##o, kB##o, xv0, xv1);
        ROWS22(DOT)
#undef DOT
#pragma unroll
        for (int mm2 = 32; mm2; mm2 >>= 1) {  // 22 interleaved butterfly chains
#define BF(o) d##o += __shfl_xor(d##o, mm2);
            ROWS22(BF)
#undef BF
        }
#define RC(o) float uu##o = inv_n / (d##o + 1e-9f);
        ROWS22(RC)
#undef RC
#define ACC_ROW(o)                                                           \
    pa.x = fmaf(kA##o.x, uu##o, pa.x); pa.y = fmaf(kA##o.y, uu##o, pa.y);    \
    pa.z = fmaf(kA##o.z, uu##o, pa.z); pa.w = fmaf(kA##o.w, uu##o, pa.w);    \
    pb.x = fmaf(kB##o.x, uu##o, pb.x); pb.y = fmaf(kB##o.y, uu##o, pb.y);    \
    pb.z = fmaf(kB##o.z, uu##o, pb.z); pb.w = fmaf(kB##o.w, uu##o, pb.w);
        ROWS22(ACC_ROW)
#undef ACC_ROW
        if (t == 19 && l == 0) {
            float* ub = u_buf + (size_t)b * NN + r_lo + w;
#define ST(o) if (w + 8 * (o) < nrows) ub[8 * (o)] = uu##o;
            ROWS22(ST)
#undef ST
        }

        // ---- phase A (streamed): rows >= 176, only in rare overflow cases -
        for (int i = 176 + w; i < nrows; i += 8) {
            const float* g0 = Kb + (size_t)(r_lo + i) * NN;
            float4 A = {0, 0, 0, 0}, B = {0, 0, 0, 0};
            if (a0) A = *(const float4*)(g0 + c0);
            if (a1) B = *(const float4*)(g0 + c1);
            float d = dot8(A, B, xv0, xv1);
#pragma unroll
            for (int mm2 = 32; mm2; mm2 >>= 1) d += __shfl_xor(d, mm2);
            float uu = inv_n / (d + 1e-9f);
            pa.x = fmaf(A.x, uu, pa.x); pa.y = fmaf(A.y, uu, pa.y);
            pa.z = fmaf(A.z, uu, pa.z); pa.w = fmaf(A.w, uu, pa.w);
            pb.x = fmaf(B.x, uu, pb.x); pb.y = fmaf(B.y, uu, pb.y);
            pb.z = fmaf(B.z, uu, pb.z); pb.w = fmaf(B.w, uu, pb.w);
            if (t == 19 && l == 0) u_buf[(size_t)b * NN + r_lo + i] = uu;
        }

        // ---- phase B: LDS reduce, publish (tag|value) u64 per column ------
        *(float4*)(pv + w * NN + c0) = pa;
        *(float4*)(pv + w * NN + c1) = pb;
        __syncthreads();
        int c = tid;  // one column per thread
        float s0 = pv[c] + pv[NN + c] + pv[2 * NN + c] + pv[3 * NN + c] +
                   pv[4 * NN + c] + pv[5 * NN + c] + pv[6 * NN + c] + pv[7 * NN + c];
        unsigned long long* pbase =
            slots64 + ((size_t)(t & 1) * 512) * 512;  // parity region
        if (S > 1) {
            unsigned long long pk =
                ((unsigned long long)(unsigned)(t + 1) << 32) | __float_as_uint(s0);
            __hip_atomic_store(pbase + (size_t)g * 512 + c, pk,
                               __ATOMIC_RELAXED, __HIP_MEMORY_SCOPE_AGENT);
        }

        // ---- phase C: poll sibling columns (1 RT), v = mu/(colsum+eps) ----
        float t0 = s0;
        for (int s = 1; s < S; s++) {
            int k = q + s; if (k >= S) k -= S;  // stagger sibling order
            const unsigned long long* p64 = pbase + (size_t)(jbase + k) * 512 + c;
            unsigned long long vpk =
                __hip_atomic_load(p64, __ATOMIC_RELAXED, __HIP_MEMORY_SCOPE_AGENT);
            while ((unsigned)(vpk >> 32) != (unsigned)(t + 1)) {
                __builtin_amdgcn_s_sleep(1);
                vpk = __hip_atomic_load(p64, __ATOMIC_RELAXED, __HIP_MEMORY_SCOPE_AGENT);
            }
            t0 += __uint_as_float((unsigned)vpk);
        }
        float v0 = (c < len) ? (inv_n / (t0 + 1e-9f)) : 0.0f;
        if (t < 19) {
            xb[c] = v0;
        } else if (c >= r_lo && c < r_lo + nrows) {
            v_buf[(size_t)b * NN + c] = v0;  // owner writes final v
        }
        __syncthreads();  // xb ready + pv consumed before next iteration
    }
}

// ---------------- kernel 4: fused epilogue, in-place on d_out -------------
__global__ __launch_bounds__(256) void epi_kernel(float* __restrict__ io,
                                                  const float* __restrict__ u,
                                                  const float* __restrict__ v,
                                                  const int* __restrict__ lengths) {
    const float E5 = 0.006737946999085467f;  // exp(-5)
    size_t idx = (size_t)blockIdx.x * 256 + threadIdx.x;  // float4 index
    int b = (int)(idx >> 16);
    int r = (int)(idx >> 7) & (NN - 1);
    int c4 = ((int)idx & 127) << 2;
    int len = max(lengths[b], 1);
    float4 o;
    if (r >= len || c4 >= len) {
        o.x = E5; o.y = E5; o.z = E5; o.w = E5;
        ((float4*)io)[idx] = o;
        return;
    }
    float4 k = ((float4*)io)[idx];
    float ui = u[(size_t)b * NN + r];
    float4 vv = *(const float4*)(v + (size_t)b * NN + c4);
    float t = (float)len * ui;
    float kv[4] = {k.x, k.y, k.z, k.w};
    float vj[4] = {vv.x, vv.y, vv.z, vv.w};
    float ov[4];
#pragma unroll
    for (int c = 0; c < 4; c++) {
        float Kc = kv[c];
        float P = t * Kc * vj[c];
        bool valid = (c4 + c) < len;
        if (valid && P > 0.1f) {
            float x = 2.5f * logf(Kc);  // == 5*sim - 5
            ov[c] = (x > 0.0f) ? (x + 1.0f) : expf(x);
        } else {
            ov[c] = E5;
        }
    }
    o.x = ov[0]; o.y = ov[1]; o.z = ov[2]; o.w = ov[3];
    ((float4*)io)[idx] = o;
}

extern "C" void kernel_launch(void* const* d_in, const int* in_sizes, int n_in,
                              void* d_out, int out_size, void* d_ws, size_t ws_size,
                              hipStream_t stream) {
    const float* h = (const float*)d_in[0];
    const float* W0 = (const float*)d_in[1];
    const float* W1 = (const float*)d_in[2];
    const int* lengths = (const int*)d_in[3];
    float* K = (float*)d_out;  // [B,N,N] K, overwritten in place by epilogue

    char* ws = (char*)d_ws;
    float* hn = (float*)ws;                                   // 33.5 MB
    size_t off = (size_t)BB * NN * DD * 4;
    float* u = (float*)(ws + off); off += (size_t)BB * NN * 4;                    // 256 KB
    float* v = (float*)(ws + off); off += (size_t)BB * NN * 4;                    // 256 KB
    unsigned long long* slots64 = (unsigned long long*)(ws + off);
    off += (size_t)2 * 512 * 512 * 8;                                             // 4.2 MB

    hn_kernel<<<BB * NN / 4, 256, 0, stream>>>(h, W0, W1, hn);
    sim_kernel<<<1024, 256, 0, stream>>>(hn, lengths, K);

    // 256 blocks x 512 thr, 1 block/CU; K cached in registers (R21 layout);
    // single-RT (tag|value) u64 exchange.
    coop_sink<<<256, 512, 0, stream>>>(K, u, v, lengths, slots64);

    epi_kernel<<<(unsigned)((size_t)BB * NN * NN / 4 / 256), 256, 0, stream>>>(K, u, v, lengths);
}

// Round 10
// 358.385 us; speedup vs baseline: 1.4685x; 1.0117x over previous
//
#include <hip/hip_runtime.h>

#define BB 128
#define NN 512
#define DD 128

// ---------------- kernel 1: h -> normalized hn ----------------
__global__ __launch_bounds__(256) void hn_kernel(const float* __restrict__ h,
                                                 const float* __restrict__ W0,
                                                 const float* __restrict__ W1,
                                                 float* __restrict__ hn) {
    int wave = (int)((blockIdx.x * blockDim.x + threadIdx.x) >> 6);  // 0..B*N-1
    int lane = threadIdx.x & 63;
    const float2* h2 = (const float2*)(h + (size_t)wave * DD);
    float2 w0 = ((const float2*)W0)[lane];
    float2 w1 = ((const float2*)W1)[lane];
    float2 x = h2[lane];
    float p0 = fmaxf(x.x * w0.x, 0.0f) * w1.x;
    float p1 = fmaxf(x.y * w0.y, 0.0f) * w1.y;
    float ss = p0 * p0 + p1 * p1;
#pragma unroll
    for (int m = 32; m; m >>= 1) ss += __shfl_xor(ss, m);
    float inv = 1.0f / (sqrtf(ss) + 1e-12f);
    float2 o;
    o.x = p0 * inv;
    o.y = p1 * inv;
    ((float2*)(hn + (size_t)wave * DD))[lane] = o;
}

// ------- kernel 2: K = exp(2*(hn hn^T + eye) - 2), SYMMETRIC tiles --------
// R25: only ti<=tj tiles computed (E[tiles/batch] 7.5 -> 5, -33% FLOPs and
// hn staging). Off-diag tiles additionally write the mirrored tile (tj,ti)
// by staging RAW acc into As (free after the k-loop) transposed in 32-row
// chunks, then coalesced row writes with the identical expf(2s-2).
// Bitwise-identical K: fmaf(a,b,c)==fmaf(b,a,c), same kc/kk accumulation
// order, eye never fires off-diagonal, expf sees the same bits.
#define KC 32
__global__ __launch_bounds__(256) void sim_kernel(const float* __restrict__ hn,
                                                  const int* __restrict__ lengths,
                                                  float* __restrict__ K) {
    __shared__ float As[KC][132];
    __shared__ float Bs[KC][132];
    __shared__ int pre[BB + 1];  // prefix sum of per-batch UPPER-TRI tile counts
    int tid = threadIdx.x;
    if (tid == 0) {
        int acc = 0;
        for (int b = 0; b < BB; b++) {
            pre[b] = acc;
            int len = max(lengths[b], 1);
            int nt = (len + 127) >> 7;
            acc += nt * (nt + 1) / 2;
        }
        pre[BB] = acc;
    }
    __syncthreads();
    int total = pre[BB];

    int lr = tid >> 3;
    int lk = (tid & 7) << 2;
    int tx = tid & 15, ty = tid >> 4;

    for (int t = blockIdx.x; t < total; t += gridDim.x) {
        int lo = 0, hi = BB;
        while (lo + 1 < hi) {
            int mid = (lo + hi) >> 1;
            if (pre[mid] <= t) lo = mid; else hi = mid;
        }
        int b = lo;
        int local = t - pre[b];
        int len = max(lengths[b], 1);
        int nt = (len + 127) >> 7;
        // decode upper-tri pair: row ti has (nt - ti) tiles (tj = ti..nt-1)
        int ti = 0, rem = local;
        while (rem >= nt - ti) { rem -= nt - ti; ti++; }
        int tj = ti + rem;
        int r0 = ti << 7, c0 = tj << 7;
        const float* base = hn + (size_t)b * NN * DD;
        float acc[8][8] = {};

        for (int kc = 0; kc < DD; kc += KC) {
#pragma unroll
            for (int rr = 0; rr < 128; rr += 32) {
                float4 a = *(const float4*)(base + (size_t)(r0 + lr + rr) * DD + kc + lk);
                As[lk + 0][lr + rr] = a.x; As[lk + 1][lr + rr] = a.y;
                As[lk + 2][lr + rr] = a.z; As[lk + 3][lr + rr] = a.w;
                float4 bb = *(const float4*)(base + (size_t)(c0 + lr + rr) * DD + kc + lk);
                Bs[lk + 0][lr + rr] = bb.x; Bs[lk + 1][lr + rr] = bb.y;
                Bs[lk + 2][lr + rr] = bb.z; Bs[lk + 3][lr + rr] = bb.w;
            }
            __syncthreads();
#pragma unroll
            for (int kk = 0; kk < KC; kk++) {
                float4 a0 = *(const float4*)&As[kk][ty * 8];
                float4 a1 = *(const float4*)&As[kk][ty * 8 + 4];
                float4 b0 = *(const float4*)&Bs[kk][tx * 4];
                float4 b1 = *(const float4*)&Bs[kk][64 + tx * 4];
                float ar[8] = {a0.x, a0.y, a0.z, a0.w, a1.x, a1.y, a1.z, a1.w};
                float bc[8] = {b0.x, b0.y, b0.z, b0.w, b1.x, b1.y, b1.z, b1.w};
#pragma unroll
                for (int r = 0; r < 8; r++)
#pragma unroll
                    for (int c = 0; c < 8; c++)
                        acc[r][c] = fmaf(ar[r], bc[c], acc[r][c]);
            }
            __syncthreads();
        }
        float* out = K + (size_t)b * NN * NN;
        // ---- direct tile (ti,tj): rows i, cols j -------------------------
#pragma unroll
        for (int r = 0; r < 8; r++) {
            int i = r0 + ty * 8 + r;
            if (i >= len) continue;
#pragma unroll
            for (int cg = 0; cg < 2; cg++) {
                int j0 = c0 + cg * 64 + tx * 4;
                if (j0 >= len) continue;
                float vv[4];
#pragma unroll
                for (int c = 0; c < 4; c++) {
                    float s = acc[r][cg * 4 + c] + ((i == j0 + c) ? 1.0f : 0.0f);
                    vv[c] = expf(2.0f * s - 2.0f);
                }
                float4 o;
                o.x = vv[0]; o.y = vv[1]; o.z = vv[2]; o.w = vv[3];
                *(float4*)(out + (size_t)i * NN + j0) = o;
            }
        }
        // ---- mirror tile (tj,ti): rows j, cols i, via LDS transpose ------
        if (ti != tj) {
#pragma unroll
            for (int cg = 0; cg < 2; cg++) {
                for (int half = 0; half < 2; half++) {
                    __syncthreads();  // As free / prev chunk consumed
                    if ((tx >> 3) == half) {
                        int jl = (tx & 7) * 4;  // j_local 0..28 within chunk
#pragma unroll
                        for (int r = 0; r < 8; r++)
#pragma unroll
                            for (int c = 0; c < 4; c++)
                                As[jl + c][ty * 8 + r] = acc[r][cg * 4 + c];
                    }
                    __syncthreads();
                    int jrow = tid >> 3;                 // 0..31
                    int j = c0 + cg * 64 + half * 32 + jrow;
                    if (j < len) {
                        int ib = (tid & 7) * 16;         // i_local base, 4 float4
#pragma unroll
                        for (int s4 = 0; s4 < 4; s4++) {
                            int il = ib + s4 * 4;
                            int i0 = r0 + il;
                            if (i0 >= len) continue;
                            float4 sraw = *(const float4*)&As[jrow][il];
                            float4 o;
                            o.x = expf(2.0f * sraw.x - 2.0f);
                            o.y = expf(2.0f * sraw.y - 2.0f);
                            o.z = expf(2.0f * sraw.z - 2.0f);
                            o.w = expf(2.0f * sraw.w - 2.0f);
                            *(float4*)(out + (size_t)j * NN + i0) = o;
                        }
                    }
                }
            }
            __syncthreads();  // last chunk consumed before next tile's staging
        }
    }
}

__device__ __forceinline__ float dot8(float4 A, float4 B, float4 x0, float4 x1) {
    float d = fmaf(A.x, x0.x, fmaf(A.y, x0.y, fmaf(A.z, x0.z, A.w * x0.w)));
    return fmaf(B.x, x1.x, fmaf(B.y, x1.y, fmaf(B.z, x1.z, fmaf(B.w, x1.w, d))));
}

// ---------------- persistent Sinkhorn: 20 iters, K register-resident ------
// R24 protocol (proven: coop 134us warm, absmax 0.0): each thread
// publishes (tag<<32 | float_bits(partial)) as ONE 8-byte relaxed agent
// atomic per column; consumers poll their own column of each sibling until
// the tag half == t+1 and take the value half from the same load. 1 RT.
#define ROWS22(X) X(0) X(1) X(2) X(3) X(4) X(5) X(6) X(7) X(8) X(9) X(10) \
    X(11) X(12) X(13) X(14) X(15) X(16) X(17) X(18) X(19) X(20) X(21)

__global__ __launch_bounds__(512, 2) void coop_sink(const float* __restrict__ K,
                                                    float* __restrict__ u_buf,
                                                    float* __restrict__ v_buf,
                                                    const int* __restrict__ lengths,
                                                    unsigned long long* __restrict__ slots64) {
    __shared__ float xb[NN];      // current multiplier vector (v)
    __shared__ float pv[8 * NN];  // per-wave column partials (16 KB)
    __shared__ int Sh[BB], Pre[BB];

    int g = blockIdx.x;
    int tid = threadIdx.x;

    // ---- deterministic GLOBAL schedule: S_b = ceil(len/176), sum <= 256 ---
    if (tid == 0) {
        int need[BB]; int ssum = 0;
        for (int m = 0; m < BB; m++) {
            int L = max(lengths[m], 1);
            need[m] = (L + 175) / 176;  // 1..3
            ssum += need[m];
        }
        while (ssum > 256) {  // rare: shrink the largest (first on tie)
            int best = 0, bv = need[0];
            for (int m = 1; m < BB; m++)
                if (need[m] > bv) { bv = need[m]; best = m; }
            need[best]--; ssum--;
        }
        int acc = 0;
        for (int m = 0; m < BB; m++) { Pre[m] = acc; Sh[m] = need[m]; acc += need[m]; }
    }
    __syncthreads();

    int m = -1;
    for (int mm = 0; mm < BB; mm++)
        if (g >= Pre[mm] && g < Pre[mm] + Sh[mm]) { m = mm; break; }
    if (m < 0) return;  // surplus block: idle
    int b = m;                  // batch
    int jbase = Pre[m];
    int q = g - jbase;          // slice within batch
    int S = Sh[m];              // slices for this batch (<=3)

    int len = max(lengths[b], 1);
    int len4 = (len + 3) & ~3;
    int rpq = (len + S - 1) / S;
    int r_lo = q * rpq;
    int nrows = min(len - r_lo, rpq);
    if (nrows < 0) nrows = 0;
    float inv_n = 1.0f / (float)len;

    int w = tid >> 6, l = tid & 63;
    int c0 = 4 * l, c1 = 256 + 4 * l;
    bool a0 = c0 < len4, a1 = c1 < len4;
    const float* Kb = K + (size_t)b * NN * NN;

    xb[tid] = (tid < len) ? 1.0f : 0.0f;

    // ---- register-resident K slice: rows w+8o (o<22), named scalars -------
#define DECL(o) float4 kA##o = {0,0,0,0}, kB##o = {0,0,0,0};
    ROWS22(DECL)
#undef DECL
#define FILL_ROW(o)                                                          \
    {                                                                        \
        int i_ = w + 8 * (o);                                                \
        if (i_ < nrows) {                                                    \
            const float* g0_ = Kb + (size_t)(r_lo + i_) * NN;                \
            if (a0) kA##o = *(const float4*)(g0_ + c0);                      \
            if (a1) kB##o = *(const float4*)(g0_ + c1);                      \
        }                                                                    \
    }
    ROWS22(FILL_ROW)
#undef FILL_ROW

    __syncthreads();

    for (int t = 0; t < 20; t++) {
        float4 xv0 = *(const float4*)(xb + c0);
        float4 xv1 = *(const float4*)(xb + c1);
        float4 pa = {0, 0, 0, 0}, pb = {0, 0, 0, 0};

        // ---- phase A (cached): 22 rows/wave entirely from registers ----
#define DOT(o) float d##o = dot8(kA##o, kB##o, xv0, xv1);
        ROWS22(DOT)
#undef DOT
#pragma unroll
        for (int mm2 = 32; mm2; mm2 >>= 1) {  // 22 interleaved butterfly chains
#define BF(o) d##o += __shfl_xor(d##o, mm2);
            ROWS22(BF)
#undef BF
        }
#define RC(o) float uu##o = inv_n / (d##o + 1e-9f);
        ROWS22(RC)
#undef RC
#define ACC_ROW(o)                                                           \
    pa.x = fmaf(kA##o.x, uu##o, pa.x); pa.y = fmaf(kA##o.y, uu##o, pa.y);    \
    pa.z = fmaf(kA##o.z, uu##o, pa.z); pa.w = fmaf(kA##o.w, uu##o, pa.w);    \
    pb.x = fmaf(kB##o.x, uu##o, pb.x); pb.y = fmaf(kB##o.y, uu##o, pb.y);    \
    pb.z = fmaf(kB##o.z, uu##o, pb.z); pb.w = fmaf(kB##o.w, uu##o, pb.w);
        ROWS22(ACC_ROW)
#undef ACC_ROW
        if (t == 19 && l == 0) {
            float* ub = u_buf + (size_t)b * NN + r_lo + w;
#define ST(o) if (w + 8 * (o) < nrows) ub[8 * (o)] = uu##o;
            ROWS22(ST)
#undef ST
        }

        // ---- phase A (streamed): rows >= 176, only in rare overflow cases -
        for (int i = 176 + w; i < nrows; i += 8) {
            const float* g0 = Kb + (size_t)(r_lo + i) * NN;
            float4 A = {0, 0, 0, 0}, B = {0, 0, 0, 0};
            if (a0) A = *(const float4*)(g0 + c0);
            if (a1) B = *(const float4*)(g0 + c1);
            float d = dot8(A, B, xv0, xv1);
#pragma unroll
            for (int mm2 = 32; mm2; mm2 >>= 1) d += __shfl_xor(d, mm2);
            float uu = inv_n / (d + 1e-9f);
            pa.x = fmaf(A.x, uu, pa.x); pa.y = fmaf(A.y, uu, pa.y);
            pa.z = fmaf(A.z, uu, pa.z); pa.w = fmaf(A.w, uu, pa.w);
            pb.x = fmaf(B.x, uu, pb.x); pb.y = fmaf(B.y, uu, pb.y);
            pb.z = fmaf(B.z, uu, pb.z); pb.w = fmaf(B.w, uu, pb.w);
            if (t == 19 && l == 0) u_buf[(size_t)b * NN + r_lo + i] = uu;
        }

        // ---- phase B: LDS reduce, publish (tag|value) u64 per column ------
        *(float4*)(pv + w * NN + c0) = pa;
        *(float4*)(pv + w * NN + c1) = pb;
        __syncthreads();
        int c = tid;  // one column per thread
        float s0 = pv[c] + pv[NN + c] + pv[2 * NN + c] + pv[3 * NN + c] +
                   pv[4 * NN + c] + pv[5 * NN + c] + pv[6 * NN + c] + pv[7 * NN + c];
        unsigned long long* pbase =
            slots64 + ((size_t)(t & 1) * 512) * 512;  // parity region
        if (S > 1) {
            unsigned long long pk =
                ((unsigned long long)(unsigned)(t + 1) << 32) | __float_as_uint(s0);
            __hip_atomic_store(pbase + (size_t)g * 512 + c, pk,
                               __ATOMIC_RELAXED, __HIP_MEMORY_SCOPE_AGENT);
        }

        // ---- phase C: poll sibling columns (1 RT), v = mu/(colsum+eps) ----
        float t0 = s0;
        for (int s = 1; s < S; s++) {
            int k = q + s; if (k >= S) k -= S;  // stagger sibling order
            const unsigned long long* p64 = pbase + (size_t)(jbase + k) * 512 + c;
            unsigned long long vpk =
                __hip_atomic_load(p64, __ATOMIC_RELAXED, __HIP_MEMORY_SCOPE_AGENT);
            while ((unsigned)(vpk >> 32) != (unsigned)(t + 1)) {
                __builtin_amdgcn_s_sleep(1);
                vpk = __hip_atomic_load(p64, __ATOMIC_RELAXED, __HIP_MEMORY_SCOPE_AGENT);
            }
            t0 += __uint_as_float((unsigned)vpk);
        }
        float v0 = (c < len) ? (inv_n / (t0 + 1e-9f)) : 0.0f;
        if (t < 19) {
            xb[c] = v0;
        } else if (c >= r_lo && c < r_lo + nrows) {
            v_buf[(size_t)b * NN + c] = v0;  // owner writes final v
        }
        __syncthreads();  // xb ready + pv consumed before next iteration
    }
}

// ---------------- kernel 4: fused epilogue, in-place on d_out -------------
__global__ __launch_bounds__(256) void epi_kernel(float* __restrict__ io,
                                                  const float* __restrict__ u,
                                                  const float* __restrict__ v,
                                                  const int* __restrict__ lengths) {
    const float E5 = 0.006737946999085467f;  // exp(-5)
    size_t idx = (size_t)blockIdx.x * 256 + threadIdx.x;  // float4 index
    int b = (int)(idx >> 16);
    int r = (int)(idx >> 7) & (NN - 1);
    int c4 = ((int)idx & 127) << 2;
    int len = max(lengths[b], 1);
    float4 o;
    if (r >= len || c4 >= len) {
        o.x = E5; o.y = E5; o.z = E5; o.w = E5;
        ((float4*)io)[idx] = o;
        return;
    }
    float4 k = ((float4*)io)[idx];
    float ui = u[(size_t)b * NN + r];
    float4 vv = *(const float4*)(v + (size_t)b * NN + c4);
    float t = (float)len * ui;
    float kv[4] = {k.x, k.y, k.z, k.w};
    float vj[4] = {vv.x, vv.y, vv.z, vv.w};
    float ov[4];
#pragma unroll
    for (int c = 0; c < 4; c++) {
        float Kc = kv[c];
        float P = t * Kc * vj[c];
        bool valid = (c4 + c) < len;
        if (valid && P > 0.1f) {
            float x = 2.5f * logf(Kc);  // == 5*sim - 5
            ov[c] = (x > 0.0f) ? (x + 1.0f) : expf(x);
        } else {
            ov[c] = E5;
        }
    }
    o.x = ov[0]; o.y = ov[1]; o.z = ov[2]; o.w = ov[3];
    ((float4*)io)[idx] = o;
}

extern "C" void kernel_launch(void* const* d_in, const int* in_sizes, int n_in,
                              void* d_out, int out_size, void* d_ws, size_t ws_size,
                              hipStream_t stream) {
    const float* h = (const float*)d_in[0];
    const float* W0 = (const float*)d_in[1];
    const float* W1 = (const float*)d_in[2];
    const int* lengths = (const int*)d_in[3];
    float* K = (float*)d_out;  // [B,N,N] K, overwritten in place by epilogue

    char* ws = (char*)d_ws;
    float* hn = (float*)ws;                                   // 33.5 MB
    size_t off = (size_t)BB * NN * DD * 4;
    float* u = (float*)(ws + off); off += (size_t)BB * NN * 4;                    // 256 KB
    float* v = (float*)(ws + off); off += (size_t)BB * NN * 4;                    // 256 KB
    unsigned long long* slots64 = (unsigned long long*)(ws + off);
    off += (size_t)2 * 512 * 512 * 8;                                             // 4.2 MB

    hn_kernel<<<BB * NN / 4, 256, 0, stream>>>(h, W0, W1, hn);
    sim_kernel<<<1024, 256, 0, stream>>>(hn, lengths, K);

    // 256 blocks x 512 thr, 1 block/CU; K cached in registers (R21 layout);
    // single-RT (tag|value) u64 exchange (R24, proven).
    coop_sink<<<256, 512, 0, stream>>>(K, u, v, lengths, slots64);

    epi_kernel<<<(unsigned)((size_t)BB * NN * NN / 4 / 256), 256, 0, stream>>>(K, u, v, lengths);
}